// Round 6
// baseline (327.206 us; speedup 1.0000x reference)
//
#include <hip/hip_runtime.h>
#include <hip/hip_bf16.h>

#define N_NODES 100000
#define N_EDGES 600000
#define HID 128
#define SCAN_NB 391          // ceil(N_NODES/256)
#define GEMM_BLOCKS 1563     // ceil(N_NODES/64)
#define FILL_BLOCKS 586

// zbuf[n] = 256 bf16: [0:128) y1 = x@W1[0:128] (gathered, src role), [128:256) xbf = bf16(x[n])
// y2buf[n] = 128 bf16: x@W1[128:256] (sequential, tgt role)
// eprs[pos] = (uint src, float-bits w) in CSR-by-target order

typedef short bf16x8 __attribute__((ext_vector_type(8)));
typedef float f32x4  __attribute__((ext_vector_type(4)));

// ---------------- helpers ----------------
__device__ inline unsigned short f2bf(float v) {
    __hip_bfloat16 h = __float2bfloat16(v);
    return *(unsigned short*)&h;
}
__device__ inline unsigned int pack2(float a, float b) {
    return (unsigned int)f2bf(a) | ((unsigned int)f2bf(b) << 16);
}
__device__ inline float2 bfpair(unsigned int u) {
    float lo = __uint_as_float(u << 16);
    float hi = __uint_as_float(u & 0xffff0000u);
    return make_float2(lo, hi);
}
// LDS-only barrier: orders ds ops; in-flight global stores may stay in flight.
__device__ inline void lds_barrier() {
    asm volatile("s_waitcnt lgkmcnt(0)" ::: "memory");
    __builtin_amdgcn_s_barrier();
}

// ---------------- prep: zero deg + W1[0:256] -> blocked bf16 [ks][n][kl] ----------------
__global__ __launch_bounds__(256) void k_prep(const float* __restrict__ W1,
                                              unsigned short* __restrict__ Bh,
                                              int* __restrict__ deg)
{
    int idx = blockIdx.x * 256 + threadIdx.x;
    if (idx < N_NODES) deg[idx] = 0;
    if (idx < 32768) {
        int n = idx & 255;
        int k = idx >> 8;                            // 0 .. 127
        float v = (n < HID) ? W1[k * HID + n] : W1[(HID + k) * HID + (n - HID)];
        Bh[(k >> 5) * 8192 + n * 32 + (k & 31)] = f2bf(v);
    }
}

// ---------------- CSR: count ----------------
__global__ __launch_bounds__(256) void k_count(const int* __restrict__ ei,
                                               int* __restrict__ deg)
{
    int e = blockIdx.x * blockDim.x + threadIdx.x;
    if (e < N_EDGES) atomicAdd(&deg[ei[N_EDGES + e]], 1);
}

// ---------------- CSR: rowptr (global prefix computed per-block from L2-hot deg) ----------------
__global__ __launch_bounds__(256) void k_rowptr(const int* __restrict__ deg,
                                                int* __restrict__ rowptr,
                                                int* __restrict__ cursor)
{
    __shared__ int s[256];
    int t = threadIdx.x;
    int b = blockIdx.x;
    int lim = b * 256;

    // base = sum of deg[0..lim) — 400 KB array is L2-resident
    int acc = 0;
    for (int i = t; i < lim; i += 256) acc += deg[i];
    s[t] = acc;
    __syncthreads();
    #pragma unroll
    for (int off = 128; off > 0; off >>= 1) {
        if (t < off) s[t] += s[t + off];
        __syncthreads();
    }
    int pb = s[0];
    __syncthreads();

    // block-local inclusive scan of degrees
    int idx = lim + t;
    int v = (idx < N_NODES) ? deg[idx] : 0;
    s[t] = v;
    __syncthreads();
    #pragma unroll
    for (int off = 1; off < 256; off <<= 1) {
        int u = (t >= off) ? s[t - off] : 0;
        __syncthreads();
        s[t] += u;
        __syncthreads();
    }
    if (idx < N_NODES) {
        int r = pb + s[t] - v;       // exclusive prefix
        rowptr[idx] = r;
        cursor[idx] = r;
    }
    if (idx == 0) rowptr[N_NODES] = N_EDGES;
}

// ---------------- CSR fill: OWN dispatch (eprs lines combine in L2 undisturbed) ----------------
__global__ __launch_bounds__(256) void k_fill(const int* __restrict__ ei,
                                              const float* __restrict__ ew,
                                              int* __restrict__ cursor,
                                              uint2* __restrict__ eprs)
{
    for (int e = blockIdx.x * 256 + threadIdx.x; e < N_EDGES; e += FILL_BLOCKS * 256) {
        int tgt = ei[N_EDGES + e];
        int pos = atomicAdd(&cursor[tgt], 1);
        eprs[pos] = make_uint2((unsigned int)ei[e], __float_as_uint(ew[e]));
    }
}

// ---------------- K-gemm: single-barrier full-K, swizzled LDS, pure full-line writes ----------------
__global__ __launch_bounds__(256) void k_gemm(const float* __restrict__ x,
                                              const unsigned short* __restrict__ BhG,
                                              unsigned short* __restrict__ zbuf,
                                              unsigned short* __restrict__ y2buf)
{
    __shared__ unsigned short Ah[64 * 128];   // 16 KB, [row][k] bf16, XOR-swizzled

    const int tid  = threadIdx.x;
    const int bm   = blockIdx.x * 64;
    const int wave = tid >> 6;
    const int lane = tid & 63;
    const int q    = lane >> 4;      // 0..3
    const int ln   = lane & 15;      // 0..15

    // ---- stage A: full 64x128 tile in ONE shot. thread (r, c) loads 32 floats. ----
    {
        const int r  = tid >> 2;         // 0..63
        const int c  = tid & 3;          // 0..3: float segment c*32 .. c*32+31
        const int gm = bm + r;
        const bool ok = gm < N_NODES;
        const float* px = &x[(size_t)gm * HID + c * 32];

        float4 v0 = make_float4(0.f,0.f,0.f,0.f), v1=v0, v2=v0, v3=v0, v4=v0, v5=v0, v6=v0, v7=v0;
        if (ok) {
            v0 = *(const float4*)(px + 0);  v1 = *(const float4*)(px + 4);
            v2 = *(const float4*)(px + 8);  v3 = *(const float4*)(px + 12);
            v4 = *(const float4*)(px + 16); v5 = *(const float4*)(px + 20);
            v6 = *(const float4*)(px + 24); v7 = *(const float4*)(px + 28);
        }
        uint4 ch0, ch1, ch2, ch3;        // 4 chunks of 16 B = 8 bf16 each
        ch0.x = pack2(v0.x, v0.y); ch0.y = pack2(v0.z, v0.w); ch0.z = pack2(v1.x, v1.y); ch0.w = pack2(v1.z, v1.w);
        ch1.x = pack2(v2.x, v2.y); ch1.y = pack2(v2.z, v2.w); ch1.z = pack2(v3.x, v3.y); ch1.w = pack2(v3.z, v3.w);
        ch2.x = pack2(v4.x, v4.y); ch2.y = pack2(v4.z, v4.w); ch2.z = pack2(v5.x, v5.y); ch2.w = pack2(v5.z, v5.w);
        ch3.x = pack2(v6.x, v6.y); ch3.y = pack2(v6.z, v6.w); ch3.z = pack2(v7.x, v7.y); ch3.w = pack2(v7.z, v7.w);

        // LDS write, swizzled: byte ^= ((row&7)<<4). row stride 256 B.
        char* rowp = (char*)Ah + r * 256;
        const int swz = (r & 7) << 4;
        *(uint4*)(rowp + ((c * 64 +  0) ^ swz)) = ch0;
        *(uint4*)(rowp + ((c * 64 + 16) ^ swz)) = ch1;
        *(uint4*)(rowp + ((c * 64 + 32) ^ swz)) = ch2;
        *(uint4*)(rowp + ((c * 64 + 48) ^ swz)) = ch3;

        // xbf half of zbuf (linear)
        if (ok) {
            unsigned short* zp = &zbuf[(size_t)gm * 256 + 128 + c * 32];
            *(uint4*)(zp + 0)  = ch0;
            *(uint4*)(zp + 8)  = ch1;
            *(uint4*)(zp + 16) = ch2;
            *(uint4*)(zp + 24) = ch3;
        }
    }
    lds_barrier();   // single barrier; zbuf stores stay in flight

    // ---- fragments: ah[mt][ks], swizzled read (row&7 == ln&7) ----
    bf16x8 ah[4][4];
    {
        const int swzr = (ln & 7) << 4;
        #pragma unroll
        for (int mt = 0; mt < 4; ++mt) {
            const char* rowp = (const char*)Ah + (mt * 16 + ln) * 256;
            #pragma unroll
            for (int ks = 0; ks < 4; ++ks) {
                ah[mt][ks] = *(const bf16x8*)(rowp + ((ks * 64 + q * 16) ^ swzr));
            }
        }
    }

    // ---- 64 MFMA, swapped operands: D = W^T . x^T -> row=hidden-out, col=node ----
    f32x4 acc[4][4] = {};            // [node-tile mt][out-tile nt]
    #pragma unroll
    for (int nt = 0; nt < 4; ++nt) {
        bf16x8 bh[4];
        #pragma unroll
        for (int ks = 0; ks < 4; ++ks) {
            bh[ks] = *(const bf16x8*)&BhG[ks * 8192 + (wave * 64 + nt * 16 + ln) * 32 + q * 8];
        }
        #pragma unroll
        for (int mt = 0; mt < 4; ++mt) {
            #pragma unroll
            for (int ks = 0; ks < 4; ++ks) {
                acc[mt][nt] = __builtin_amdgcn_mfma_f32_16x16x32_bf16(bh[ks], ah[mt][ks], acc[mt][nt], 0, 0, 0);
            }
        }
    }

    // ---- epilogue: D col=ln -> node, row=q*4+r -> hidden-out; one uint2 per (mt,nt) ----
    #pragma unroll
    for (int mt = 0; mt < 4; ++mt) {
        int node = bm + mt * 16 + ln;
        if (node < N_NODES) {
            #pragma unroll
            for (int nt = 0; nt < 4; ++nt) {
                int col0 = wave * 64 + nt * 16 + q * 4;
                unsigned int lo = pack2(acc[mt][nt][0], acc[mt][nt][1]);
                unsigned int hi = pack2(acc[mt][nt][2], acc[mt][nt][3]);
                if (col0 < 128) *(uint2*)&zbuf[(size_t)node * 256 + col0] = make_uint2(lo, hi);
                else            *(uint2*)&y2buf[(size_t)node * 128 + (col0 - 128)] = make_uint2(lo, hi);
            }
        }
    }
}

// ---------------- fused scores + softmax + aggregation (unchanged) ----------------
__global__ __launch_bounds__(256) void k_fused(const unsigned int* __restrict__ zu,
                                               const unsigned int* __restrict__ y2u,
                                               const int* __restrict__ rowptr,
                                               const uint2* __restrict__ eprs,
                                               const float* __restrict__ x,
                                               const float* __restrict__ W1,
                                               const float* __restrict__ b1,
                                               const float* __restrict__ W2,
                                               const float* __restrict__ b2,
                                               float* __restrict__ out)
{
    int n = (blockIdx.x * blockDim.x + threadIdx.x) >> 6;
    int lane = threadIdx.x & 63;
    if (n >= N_NODES) return;
    int ql = lane & 15;      // position within quarter: cols ql*8 .. ql*8+7
    int qi = lane >> 4;      // quarter index 0..3 (edge slot)
    int c0 = ql * 8;

    // per-lane constants for 8 cols
    uint4 uy2 = *(const uint4*)&y2u[(size_t)n * 64 + ql * 4];
    float2 y2a = bfpair(uy2.x), y2b = bfpair(uy2.y), y2c = bfpair(uy2.z), y2d = bfpair(uy2.w);
    float4 bv0 = *(const float4*)&b1[c0];
    float4 bv1 = *(const float4*)&b1[c0 + 4];
    float4 wr0 = *(const float4*)&W1[256 * HID + c0];
    float4 wr1 = *(const float4*)&W1[256 * HID + c0 + 4];
    float4 w20 = *(const float4*)&W2[c0];
    float4 w21 = *(const float4*)&W2[c0 + 4];
    float p0 = y2a.x + bv0.x, p1 = y2a.y + bv0.y, p2 = y2b.x + bv0.z, p3 = y2b.y + bv0.w;
    float p4 = y2c.x + bv1.x, p5 = y2c.y + bv1.y, p6 = y2d.x + bv1.z, p7 = y2d.y + bv1.w;
    float b2v = b2[0];

    int beg = rowptr[n], end = rowptr[n + 1];
    float a0 = 0.f, a1 = 0.f, a2 = 0.f, a3 = 0.f;
    float a4 = 0.f, a5 = 0.f, a6 = 0.f, a7 = 0.f;
    float denom = 0.f;

    for (int i = beg; i < end; i += 4) {
        int idx = i + qi;
        bool valid = idx < end;
        int ie = valid ? idx : (end - 1);
        uint2 ep = eprs[ie];
        size_t base = (size_t)ep.x * 128;
        float w = __uint_as_float(ep.y);
        uint4 uy = *(const uint4*)&zu[base + ql * 4];
        uint4 ux = *(const uint4*)&zu[base + 64 + ql * 4];

        float2 ya = bfpair(uy.x), yb = bfpair(uy.y), yc = bfpair(uy.z), yd = bfpair(uy.w);
        float h0 = fmaxf(fmaf(w, wr0.x, ya.x + p0), 0.f);
        float h1 = fmaxf(fmaf(w, wr0.y, ya.y + p1), 0.f);
        float h2 = fmaxf(fmaf(w, wr0.z, yb.x + p2), 0.f);
        float h3 = fmaxf(fmaf(w, wr0.w, yb.y + p3), 0.f);
        float h4 = fmaxf(fmaf(w, wr1.x, yc.x + p4), 0.f);
        float h5 = fmaxf(fmaf(w, wr1.y, yc.y + p5), 0.f);
        float h6 = fmaxf(fmaf(w, wr1.z, yd.x + p6), 0.f);
        float h7 = fmaxf(fmaf(w, wr1.w, yd.y + p7), 0.f);
        float s = ((h0 * w20.x + h1 * w20.y) + (h2 * w20.z + h3 * w20.w))
                + ((h4 * w21.x + h5 * w21.y) + (h6 * w21.z + h7 * w21.w));
        // reduce within quarter (xor masks 1,2,4,8 stay in the 16-lane group)
        #pragma unroll
        for (int m = 1; m <= 8; m <<= 1) s += __shfl_xor(s, m, 64);
        float es = valid ? __expf(s + b2v) : 0.f;

        float2 xa = bfpair(ux.x), xb = bfpair(ux.y), xc = bfpair(ux.z), xd = bfpair(ux.w);
        a0 = fmaf(es, xa.x, a0); a1 = fmaf(es, xa.y, a1);
        a2 = fmaf(es, xb.x, a2); a3 = fmaf(es, xb.y, a3);
        a4 = fmaf(es, xc.x, a4); a5 = fmaf(es, xc.y, a5);
        a6 = fmaf(es, xd.x, a6); a7 = fmaf(es, xd.y, a7);
        denom += es;
    }

    // merge quarters (each quarter's lane ql covers the same 8 cols)
    #pragma unroll
    for (int m = 16; m <= 32; m <<= 1) {
        a0 += __shfl_xor(a0, m, 64); a1 += __shfl_xor(a1, m, 64);
        a2 += __shfl_xor(a2, m, 64); a3 += __shfl_xor(a3, m, 64);
        a4 += __shfl_xor(a4, m, 64); a5 += __shfl_xor(a5, m, 64);
        a6 += __shfl_xor(a6, m, 64); a7 += __shfl_xor(a7, m, 64);
        denom += __shfl_xor(denom, m, 64);
    }

    if (qi == 0) {
        float4 xt0 = *(const float4*)&x[(size_t)n * HID + c0];
        float4 xt1 = *(const float4*)&x[(size_t)n * HID + c0 + 4];
        float inv = 1.0f / fmaxf(denom, 1e-12f);
        float4 o0, o1;
        o0.x = xt0.x + a0 * inv; o0.y = xt0.y + a1 * inv;
        o0.z = xt0.z + a2 * inv; o0.w = xt0.w + a3 * inv;
        o1.x = xt1.x + a4 * inv; o1.y = xt1.y + a5 * inv;
        o1.z = xt1.z + a6 * inv; o1.w = xt1.w + a7 * inv;
        *(float4*)&out[(size_t)n * HID + c0]     = o0;
        *(float4*)&out[(size_t)n * HID + c0 + 4] = o1;
    }
}

// ---------------- launch ----------------
extern "C" void kernel_launch(void* const* d_in, const int* in_sizes, int n_in,
                              void* d_out, int out_size, void* d_ws, size_t ws_size,
                              hipStream_t stream) {
    const float* x  = (const float*)d_in[0];
    const int*   ei = (const int*)d_in[1];
    const float* ew = (const float*)d_in[2];
    const float* W1 = (const float*)d_in[3];
    const float* b1 = (const float*)d_in[4];
    const float* W2 = (const float*)d_in[5];
    const float* b2 = (const float*)d_in[6];
    float* out = (float*)d_out;
    char* ws = (char*)d_ws;

    const size_t deg_b    = 400000;
    const size_t rowptr_b = 400016;
    const size_t cursor_b = 400000;
    const size_t eprs_b   = 4800000;     // N_EDGES * 8
    const size_t part_b   = 1568;        // (unused, kept for layout stability)
    const size_t pb_b     = 1568;        // (unused, kept for layout stability)
    const size_t Bh_b     = 65536;

    char* p = ws;
    int* deg      = (int*)p;             p += deg_b;
    int* rowptr   = (int*)p;             p += rowptr_b;
    int* cursor   = (int*)p;             p += cursor_b;
    uint2* eprs   = (uint2*)p;           p += eprs_b;
    p += part_b;
    p += pb_b;
    unsigned short* BhG = (unsigned short*)p;  p += Bh_b;
    unsigned short* zbuf  = (unsigned short*)p;  p += (size_t)N_NODES * 256 * 2;  // 51.2 MB
    unsigned short* y2buf = (unsigned short*)p;                                   // 25.6 MB

    const int edge_blocks = (N_EDGES + 255) / 256;
    const int node_wave_blocks = (N_NODES * 64 + 255) / 256;

    hipLaunchKernelGGL(k_prep,   dim3(SCAN_NB), dim3(256), 0, stream, W1, BhG, deg);
    hipLaunchKernelGGL(k_count,  dim3(edge_blocks), dim3(256), 0, stream, ei, deg);
    hipLaunchKernelGGL(k_rowptr, dim3(SCAN_NB), dim3(256), 0, stream, deg, rowptr, cursor);
    hipLaunchKernelGGL(k_fill,   dim3(FILL_BLOCKS), dim3(256), 0, stream, ei, ew, cursor, eprs);
    hipLaunchKernelGGL(k_gemm,   dim3(GEMM_BLOCKS), dim3(256), 0, stream, x, BhG, zbuf, y2buf);
    hipLaunchKernelGGL(k_fused,  dim3(node_wave_blocks), dim3(256), 0, stream,
                       (const unsigned int*)zbuf, (const unsigned int*)y2buf,
                       rowptr, eprs, x, W1, b1, W2, b2, out);
}

// Round 7
// 319.624 us; speedup vs baseline: 1.0237x; 1.0237x over previous
//
#include <hip/hip_runtime.h>
#include <hip/hip_bf16.h>

#define N_NODES 100000
#define N_EDGES 600000
#define HID 128
#define SCAN_NB 391          // ceil(N_NODES/256)
#define GEMM_BLOCKS 1563     // ceil(N_NODES/64)
#define FILL_BLOCKS 586

// zbuf[n] = 256 bf16: [0:128) y1 = x@W1[0:128] (gathered, src role), [128:256) xbf = bf16(x[n])
// y2buf[n] = 128 bf16: x@W1[128:256] (sequential, tgt role)
// eprs[pos] = (uint src, float-bits w) in CSR-by-target order

typedef short bf16x8 __attribute__((ext_vector_type(8)));
typedef float f32x4  __attribute__((ext_vector_type(4)));

// ---------------- helpers ----------------
__device__ inline unsigned short f2bf(float v) {
    __hip_bfloat16 h = __float2bfloat16(v);
    return *(unsigned short*)&h;
}
__device__ inline unsigned int pack2(float a, float b) {
    return (unsigned int)f2bf(a) | ((unsigned int)f2bf(b) << 16);
}
__device__ inline float2 bfpair(unsigned int u) {
    float lo = __uint_as_float(u << 16);
    float hi = __uint_as_float(u & 0xffff0000u);
    return make_float2(lo, hi);
}
// LDS-only barrier: orders ds ops; in-flight global stores may stay in flight.
__device__ inline void lds_barrier() {
    asm volatile("s_waitcnt lgkmcnt(0)" ::: "memory");
    __builtin_amdgcn_s_barrier();
}

// ---------------- prep: zero deg + W1[0:256] -> blocked bf16 [ks][n][kl] ----------------
__global__ __launch_bounds__(256) void k_prep(const float* __restrict__ W1,
                                              unsigned short* __restrict__ Bh,
                                              int* __restrict__ deg)
{
    int idx = blockIdx.x * 256 + threadIdx.x;
    if (idx < N_NODES) deg[idx] = 0;
    if (idx < 32768) {
        int n = idx & 255;
        int k = idx >> 8;                            // 0 .. 127
        float v = (n < HID) ? W1[k * HID + n] : W1[(HID + k) * HID + (n - HID)];
        Bh[(k >> 5) * 8192 + n * 32 + (k & 31)] = f2bf(v);
    }
}

// ---------------- CSR: count ----------------
__global__ __launch_bounds__(256) void k_count(const int* __restrict__ ei,
                                               int* __restrict__ deg)
{
    int e = blockIdx.x * blockDim.x + threadIdx.x;
    if (e < N_EDGES) atomicAdd(&deg[ei[N_EDGES + e]], 1);
}

// ---------------- CSR: rowptr (global prefix computed per-block from L2-hot deg) ----------------
__global__ __launch_bounds__(256) void k_rowptr(const int* __restrict__ deg,
                                                int* __restrict__ rowptr,
                                                int* __restrict__ cursor)
{
    __shared__ int s[256];
    int t = threadIdx.x;
    int b = blockIdx.x;
    int lim = b * 256;

    // base = sum of deg[0..lim) — 400 KB array is L2-resident
    int acc = 0;
    for (int i = t; i < lim; i += 256) acc += deg[i];
    s[t] = acc;
    __syncthreads();
    #pragma unroll
    for (int off = 128; off > 0; off >>= 1) {
        if (t < off) s[t] += s[t + off];
        __syncthreads();
    }
    int pb = s[0];
    __syncthreads();

    // block-local inclusive scan of degrees
    int idx = lim + t;
    int v = (idx < N_NODES) ? deg[idx] : 0;
    s[t] = v;
    __syncthreads();
    #pragma unroll
    for (int off = 1; off < 256; off <<= 1) {
        int u = (t >= off) ? s[t - off] : 0;
        __syncthreads();
        s[t] += u;
        __syncthreads();
    }
    if (idx < N_NODES) {
        int r = pb + s[t] - v;       // exclusive prefix
        rowptr[idx] = r;
        cursor[idx] = r;
    }
    if (idx == 0) rowptr[N_NODES] = N_EDGES;
}

// ---------------- hybrid: K-gemm (single-barrier, swizzled LDS) + fill appended LAST (R3 order) ----------------
__global__ __launch_bounds__(256) void k_gemm_fill(const float* __restrict__ x,
                                                   const unsigned short* __restrict__ BhG,
                                                   unsigned short* __restrict__ zbuf,
                                                   unsigned short* __restrict__ y2buf,
                                                   const int* __restrict__ ei,
                                                   const float* __restrict__ ew,
                                                   int* __restrict__ cursor,
                                                   uint2* __restrict__ eprs)
{
    __shared__ unsigned short Ah[64 * 128];   // 16 KB, [row][k] bf16, XOR-swizzled

    if (blockIdx.x >= GEMM_BLOCKS) {
        // ---- fill role LAST: scatter latency hides under the gemm tail (R3-proven order) ----
        int fb = blockIdx.x - GEMM_BLOCKS;
        for (int e = fb * 256 + threadIdx.x; e < N_EDGES; e += FILL_BLOCKS * 256) {
            int tgt = ei[N_EDGES + e];
            int pos = atomicAdd(&cursor[tgt], 1);
            eprs[pos] = make_uint2((unsigned int)ei[e], __float_as_uint(ew[e]));
        }
        return;
    }

    const int tid  = threadIdx.x;
    const int bm   = blockIdx.x * 64;
    const int wave = tid >> 6;
    const int lane = tid & 63;
    const int q    = lane >> 4;      // 0..3
    const int ln   = lane & 15;      // 0..15

    // ---- stage A: full 64x128 tile in ONE shot. thread (r, c) loads 32 floats. ----
    {
        const int r  = tid >> 2;         // 0..63
        const int c  = tid & 3;          // 0..3: float segment c*32 .. c*32+31
        const int gm = bm + r;
        const bool ok = gm < N_NODES;
        const float* px = &x[(size_t)gm * HID + c * 32];

        float4 v0 = make_float4(0.f,0.f,0.f,0.f), v1=v0, v2=v0, v3=v0, v4=v0, v5=v0, v6=v0, v7=v0;
        if (ok) {
            v0 = *(const float4*)(px + 0);  v1 = *(const float4*)(px + 4);
            v2 = *(const float4*)(px + 8);  v3 = *(const float4*)(px + 12);
            v4 = *(const float4*)(px + 16); v5 = *(const float4*)(px + 20);
            v6 = *(const float4*)(px + 24); v7 = *(const float4*)(px + 28);
        }
        uint4 ch0, ch1, ch2, ch3;        // 4 chunks of 16 B = 8 bf16 each
        ch0.x = pack2(v0.x, v0.y); ch0.y = pack2(v0.z, v0.w); ch0.z = pack2(v1.x, v1.y); ch0.w = pack2(v1.z, v1.w);
        ch1.x = pack2(v2.x, v2.y); ch1.y = pack2(v2.z, v2.w); ch1.z = pack2(v3.x, v3.y); ch1.w = pack2(v3.z, v3.w);
        ch2.x = pack2(v4.x, v4.y); ch2.y = pack2(v4.z, v4.w); ch2.z = pack2(v5.x, v5.y); ch2.w = pack2(v5.z, v5.w);
        ch3.x = pack2(v6.x, v6.y); ch3.y = pack2(v6.z, v6.w); ch3.z = pack2(v7.x, v7.y); ch3.w = pack2(v7.z, v7.w);

        // LDS write, swizzled: byte ^= ((row&7)<<4). row stride 256 B.
        char* rowp = (char*)Ah + r * 256;
        const int swz = (r & 7) << 4;
        *(uint4*)(rowp + ((c * 64 +  0) ^ swz)) = ch0;
        *(uint4*)(rowp + ((c * 64 + 16) ^ swz)) = ch1;
        *(uint4*)(rowp + ((c * 64 + 32) ^ swz)) = ch2;
        *(uint4*)(rowp + ((c * 64 + 48) ^ swz)) = ch3;

        // xbf half of zbuf (linear)
        if (ok) {
            unsigned short* zp = &zbuf[(size_t)gm * 256 + 128 + c * 32];
            *(uint4*)(zp + 0)  = ch0;
            *(uint4*)(zp + 8)  = ch1;
            *(uint4*)(zp + 16) = ch2;
            *(uint4*)(zp + 24) = ch3;
        }
    }
    lds_barrier();   // single barrier; zbuf stores stay in flight

    // ---- fragments: ah[mt][ks], swizzled read (row&7 == ln&7) ----
    bf16x8 ah[4][4];
    {
        const int swzr = (ln & 7) << 4;
        #pragma unroll
        for (int mt = 0; mt < 4; ++mt) {
            const char* rowp = (const char*)Ah + (mt * 16 + ln) * 256;
            #pragma unroll
            for (int ks = 0; ks < 4; ++ks) {
                ah[mt][ks] = *(const bf16x8*)(rowp + ((ks * 64 + q * 16) ^ swzr));
            }
        }
    }

    // ---- 64 MFMA, swapped operands: D = W^T . x^T -> row=hidden-out, col=node ----
    f32x4 acc[4][4] = {};            // [node-tile mt][out-tile nt]
    #pragma unroll
    for (int nt = 0; nt < 4; ++nt) {
        bf16x8 bh[4];
        #pragma unroll
        for (int ks = 0; ks < 4; ++ks) {
            bh[ks] = *(const bf16x8*)&BhG[ks * 8192 + (wave * 64 + nt * 16 + ln) * 32 + q * 8];
        }
        #pragma unroll
        for (int mt = 0; mt < 4; ++mt) {
            #pragma unroll
            for (int ks = 0; ks < 4; ++ks) {
                acc[mt][nt] = __builtin_amdgcn_mfma_f32_16x16x32_bf16(bh[ks], ah[mt][ks], acc[mt][nt], 0, 0, 0);
            }
        }
    }

    // ---- epilogue: D col=ln -> node, row=q*4+r -> hidden-out; one uint2 per (mt,nt) ----
    #pragma unroll
    for (int mt = 0; mt < 4; ++mt) {
        int node = bm + mt * 16 + ln;
        if (node < N_NODES) {
            #pragma unroll
            for (int nt = 0; nt < 4; ++nt) {
                int col0 = wave * 64 + nt * 16 + q * 4;
                unsigned int lo = pack2(acc[mt][nt][0], acc[mt][nt][1]);
                unsigned int hi = pack2(acc[mt][nt][2], acc[mt][nt][3]);
                if (col0 < 128) *(uint2*)&zbuf[(size_t)node * 256 + col0] = make_uint2(lo, hi);
                else            *(uint2*)&y2buf[(size_t)node * 128 + (col0 - 128)] = make_uint2(lo, hi);
            }
        }
    }
}

// ---------------- fused scores + softmax + aggregation: 8 edges / iteration ----------------
__global__ __launch_bounds__(256) void k_fused(const unsigned int* __restrict__ zu,
                                               const unsigned int* __restrict__ y2u,
                                               const int* __restrict__ rowptr,
                                               const uint2* __restrict__ eprs,
                                               const float* __restrict__ x,
                                               const float* __restrict__ W1,
                                               const float* __restrict__ b1,
                                               const float* __restrict__ W2,
                                               const float* __restrict__ b2,
                                               float* __restrict__ out)
{
    int n = (blockIdx.x * blockDim.x + threadIdx.x) >> 6;
    int lane = threadIdx.x & 63;
    if (n >= N_NODES) return;
    int ql = lane & 15;      // position within quarter: cols ql*8 .. ql*8+7
    int qi = lane >> 4;      // quarter index 0..3 (edge slot)
    int c0 = ql * 8;

    // per-lane constants for 8 cols
    uint4 uy2 = *(const uint4*)&y2u[(size_t)n * 64 + ql * 4];
    float2 y2a = bfpair(uy2.x), y2b = bfpair(uy2.y), y2c = bfpair(uy2.z), y2d = bfpair(uy2.w);
    float4 bv0 = *(const float4*)&b1[c0];
    float4 bv1 = *(const float4*)&b1[c0 + 4];
    float4 wr0 = *(const float4*)&W1[256 * HID + c0];
    float4 wr1 = *(const float4*)&W1[256 * HID + c0 + 4];
    float4 w20 = *(const float4*)&W2[c0];
    float4 w21 = *(const float4*)&W2[c0 + 4];
    float p0 = y2a.x + bv0.x, p1 = y2a.y + bv0.y, p2 = y2b.x + bv0.z, p3 = y2b.y + bv0.w;
    float p4 = y2c.x + bv1.x, p5 = y2c.y + bv1.y, p6 = y2d.x + bv1.z, p7 = y2d.y + bv1.w;
    float b2v = b2[0];

    int beg = rowptr[n], end = rowptr[n + 1];
    float a0 = 0.f, a1 = 0.f, a2 = 0.f, a3 = 0.f;
    float a4 = 0.f, a5 = 0.f, a6 = 0.f, a7 = 0.f;
    float denom = 0.f;

    for (int i = beg; i < end; i += 8) {
        // two edge slots per quarter: A = i+qi, B = i+4+qi. Issue ALL loads first.
        int idxA = i + qi;
        int idxB = i + 4 + qi;
        bool vA = idxA < end;
        bool vB = idxB < end;
        int ieA = vA ? idxA : (end - 1);
        int ieB = vB ? idxB : (end - 1);
        uint2 epA = eprs[ieA];
        uint2 epB = eprs[ieB];
        size_t baseA = (size_t)epA.x * 128;
        size_t baseB = (size_t)epB.x * 128;
        float wa = __uint_as_float(epA.y);
        float wb = __uint_as_float(epB.y);
        uint4 uyA = *(const uint4*)&zu[baseA + ql * 4];
        uint4 uxA = *(const uint4*)&zu[baseA + 64 + ql * 4];
        uint4 uyB = *(const uint4*)&zu[baseB + ql * 4];
        uint4 uxB = *(const uint4*)&zu[baseB + 64 + ql * 4];

        // ---- edge A score ----
        float2 ya = bfpair(uyA.x), yb = bfpair(uyA.y), yc = bfpair(uyA.z), yd = bfpair(uyA.w);
        float h0 = fmaxf(fmaf(wa, wr0.x, ya.x + p0), 0.f);
        float h1 = fmaxf(fmaf(wa, wr0.y, ya.y + p1), 0.f);
        float h2 = fmaxf(fmaf(wa, wr0.z, yb.x + p2), 0.f);
        float h3 = fmaxf(fmaf(wa, wr0.w, yb.y + p3), 0.f);
        float h4 = fmaxf(fmaf(wa, wr1.x, yc.x + p4), 0.f);
        float h5 = fmaxf(fmaf(wa, wr1.y, yc.y + p5), 0.f);
        float h6 = fmaxf(fmaf(wa, wr1.z, yd.x + p6), 0.f);
        float h7 = fmaxf(fmaf(wa, wr1.w, yd.y + p7), 0.f);
        float sA = ((h0 * w20.x + h1 * w20.y) + (h2 * w20.z + h3 * w20.w))
                 + ((h4 * w21.x + h5 * w21.y) + (h6 * w21.z + h7 * w21.w));

        // ---- edge B score (independent chain) ----
        float2 za = bfpair(uyB.x), zb = bfpair(uyB.y), zc = bfpair(uyB.z), zd = bfpair(uyB.w);
        float g0 = fmaxf(fmaf(wb, wr0.x, za.x + p0), 0.f);
        float g1 = fmaxf(fmaf(wb, wr0.y, za.y + p1), 0.f);
        float g2 = fmaxf(fmaf(wb, wr0.z, zb.x + p2), 0.f);
        float g3 = fmaxf(fmaf(wb, wr0.w, zb.y + p3), 0.f);
        float g4 = fmaxf(fmaf(wb, wr1.x, zc.x + p4), 0.f);
        float g5 = fmaxf(fmaf(wb, wr1.y, zc.y + p5), 0.f);
        float g6 = fmaxf(fmaf(wb, wr1.z, zd.x + p6), 0.f);
        float g7 = fmaxf(fmaf(wb, wr1.w, zd.y + p7), 0.f);
        float sB = ((g0 * w20.x + g1 * w20.y) + (g2 * w20.z + g3 * w20.w))
                 + ((g4 * w21.x + g5 * w21.y) + (g6 * w21.z + g7 * w21.w));

        // reduce within quarter — two independent chains
        #pragma unroll
        for (int m = 1; m <= 8; m <<= 1) {
            sA += __shfl_xor(sA, m, 64);
            sB += __shfl_xor(sB, m, 64);
        }
        float esA = vA ? __expf(sA + b2v) : 0.f;
        float esB = vB ? __expf(sB + b2v) : 0.f;

        float2 xa = bfpair(uxA.x), xb = bfpair(uxA.y), xc = bfpair(uxA.z), xd = bfpair(uxA.w);
        float2 ua = bfpair(uxB.x), ub = bfpair(uxB.y), uc = bfpair(uxB.z), ud = bfpair(uxB.w);
        a0 = fmaf(esA, xa.x, fmaf(esB, ua.x, a0));
        a1 = fmaf(esA, xa.y, fmaf(esB, ua.y, a1));
        a2 = fmaf(esA, xb.x, fmaf(esB, ub.x, a2));
        a3 = fmaf(esA, xb.y, fmaf(esB, ub.y, a3));
        a4 = fmaf(esA, xc.x, fmaf(esB, uc.x, a4));
        a5 = fmaf(esA, xc.y, fmaf(esB, uc.y, a5));
        a6 = fmaf(esA, xd.x, fmaf(esB, ud.x, a6));
        a7 = fmaf(esA, xd.y, fmaf(esB, ud.y, a7));
        denom += esA + esB;
    }

    // merge quarters (each quarter's lane ql covers the same 8 cols)
    #pragma unroll
    for (int m = 16; m <= 32; m <<= 1) {
        a0 += __shfl_xor(a0, m, 64); a1 += __shfl_xor(a1, m, 64);
        a2 += __shfl_xor(a2, m, 64); a3 += __shfl_xor(a3, m, 64);
        a4 += __shfl_xor(a4, m, 64); a5 += __shfl_xor(a5, m, 64);
        a6 += __shfl_xor(a6, m, 64); a7 += __shfl_xor(a7, m, 64);
        denom += __shfl_xor(denom, m, 64);
    }

    if (qi == 0) {
        float4 xt0 = *(const float4*)&x[(size_t)n * HID + c0];
        float4 xt1 = *(const float4*)&x[(size_t)n * HID + c0 + 4];
        float inv = 1.0f / fmaxf(denom, 1e-12f);
        float4 o0, o1;
        o0.x = xt0.x + a0 * inv; o0.y = xt0.y + a1 * inv;
        o0.z = xt0.z + a2 * inv; o0.w = xt0.w + a3 * inv;
        o1.x = xt1.x + a4 * inv; o1.y = xt1.y + a5 * inv;
        o1.z = xt1.z + a6 * inv; o1.w = xt1.w + a7 * inv;
        *(float4*)&out[(size_t)n * HID + c0]     = o0;
        *(float4*)&out[(size_t)n * HID + c0 + 4] = o1;
    }
}

// ---------------- launch ----------------
extern "C" void kernel_launch(void* const* d_in, const int* in_sizes, int n_in,
                              void* d_out, int out_size, void* d_ws, size_t ws_size,
                              hipStream_t stream) {
    const float* x  = (const float*)d_in[0];
    const int*   ei = (const int*)d_in[1];
    const float* ew = (const float*)d_in[2];
    const float* W1 = (const float*)d_in[3];
    const float* b1 = (const float*)d_in[4];
    const float* W2 = (const float*)d_in[5];
    const float* b2 = (const float*)d_in[6];
    float* out = (float*)d_out;
    char* ws = (char*)d_ws;

    const size_t deg_b    = 400000;
    const size_t rowptr_b = 400016;
    const size_t cursor_b = 400000;
    const size_t eprs_b   = 4800000;     // N_EDGES * 8
    const size_t part_b   = 1568;        // (unused, kept for layout stability)
    const size_t pb_b     = 1568;        // (unused, kept for layout stability)
    const size_t Bh_b     = 65536;

    char* p = ws;
    int* deg      = (int*)p;             p += deg_b;
    int* rowptr   = (int*)p;             p += rowptr_b;
    int* cursor   = (int*)p;             p += cursor_b;
    uint2* eprs   = (uint2*)p;           p += eprs_b;
    p += part_b;
    p += pb_b;
    unsigned short* BhG = (unsigned short*)p;  p += Bh_b;
    unsigned short* zbuf  = (unsigned short*)p;  p += (size_t)N_NODES * 256 * 2;  // 51.2 MB
    unsigned short* y2buf = (unsigned short*)p;                                   // 25.6 MB

    const int edge_blocks = (N_EDGES + 255) / 256;
    const int node_wave_blocks = (N_NODES * 64 + 255) / 256;

    hipLaunchKernelGGL(k_prep,   dim3(SCAN_NB), dim3(256), 0, stream, W1, BhG, deg);
    hipLaunchKernelGGL(k_count,  dim3(edge_blocks), dim3(256), 0, stream, ei, deg);
    hipLaunchKernelGGL(k_rowptr, dim3(SCAN_NB), dim3(256), 0, stream, deg, rowptr, cursor);
    hipLaunchKernelGGL(k_gemm_fill, dim3(GEMM_BLOCKS + FILL_BLOCKS), dim3(256), 0, stream,
                       x, BhG, zbuf, y2buf, ei, ew, cursor, eprs);
    hipLaunchKernelGGL(k_fused,  dim3(node_wave_blocks), dim3(256), 0, stream,
                       (const unsigned int*)zbuf, (const unsigned int*)y2buf,
                       rowptr, eprs, x, W1, b1, W2, b2, out);
}

// Round 8
// 317.908 us; speedup vs baseline: 1.0292x; 1.0054x over previous
//
#include <hip/hip_runtime.h>
#include <hip/hip_bf16.h>

#define N_NODES 100000
#define N_EDGES 600000
#define HID 128
#define SCAN_NB 391          // ceil(N_NODES/256)
#define GEMM_BLOCKS 1563     // ceil(N_NODES/64)
#define EDGES_PER_BLOCK 384  // ceil(N_EDGES/GEMM_BLOCKS)

// zbuf[n] = 256 bf16: [0:128) y1 = x@W1[0:128] (gathered, src role), [128:256) xbf = bf16(x[n])
// y2buf[n] = 128 bf16: x@W1[128:256] (sequential, tgt role)
// eprs[pos] = (uint src, float-bits w) in CSR-by-target order (within-node order = count order, arbitrary)

typedef short bf16x8 __attribute__((ext_vector_type(8)));
typedef float f32x4  __attribute__((ext_vector_type(4)));

// ---------------- helpers ----------------
__device__ inline unsigned short f2bf(float v) {
    __hip_bfloat16 h = __float2bfloat16(v);
    return *(unsigned short*)&h;
}
__device__ inline unsigned int pack2(float a, float b) {
    return (unsigned int)f2bf(a) | ((unsigned int)f2bf(b) << 16);
}
__device__ inline float2 bfpair(unsigned int u) {
    float lo = __uint_as_float(u << 16);
    float hi = __uint_as_float(u & 0xffff0000u);
    return make_float2(lo, hi);
}
// LDS-only barrier: orders ds ops; in-flight global stores may stay in flight.
__device__ inline void lds_barrier() {
    asm volatile("s_waitcnt lgkmcnt(0)" ::: "memory");
    __builtin_amdgcn_s_barrier();
}

// ---------------- prep: zero deg + W1[0:256] -> blocked bf16 [ks][n][kl] ----------------
__global__ __launch_bounds__(256) void k_prep(const float* __restrict__ W1,
                                              unsigned short* __restrict__ Bh,
                                              int* __restrict__ deg)
{
    int idx = blockIdx.x * 256 + threadIdx.x;
    if (idx < N_NODES) deg[idx] = 0;
    if (idx < 32768) {
        int n = idx & 255;
        int k = idx >> 8;                            // 0 .. 127
        float v = (n < HID) ? W1[k * HID + n] : W1[(HID + k) * HID + (n - HID)];
        Bh[(k >> 5) * 8192 + n * 32 + (k & 31)] = f2bf(v);
    }
}

// ---------------- CSR: count + per-edge rank (atomic return kept) ----------------
__global__ __launch_bounds__(256) void k_count(const int* __restrict__ ei,
                                               int* __restrict__ deg,
                                               int* __restrict__ rank)
{
    int e = blockIdx.x * blockDim.x + threadIdx.x;
    if (e < N_EDGES) rank[e] = atomicAdd(&deg[ei[N_EDGES + e]], 1);
}

// ---------------- CSR: rowptr (global prefix computed per-block from L2-hot deg) ----------------
__global__ __launch_bounds__(256) void k_rowptr(const int* __restrict__ deg,
                                                int* __restrict__ rowptr)
{
    __shared__ int s[256];
    int t = threadIdx.x;
    int b = blockIdx.x;
    int lim = b * 256;

    // base = sum of deg[0..lim) — 400 KB array is L2-resident
    int acc = 0;
    for (int i = t; i < lim; i += 256) acc += deg[i];
    s[t] = acc;
    __syncthreads();
    #pragma unroll
    for (int off = 128; off > 0; off >>= 1) {
        if (t < off) s[t] += s[t + off];
        __syncthreads();
    }
    int pb = s[0];
    __syncthreads();

    // block-local inclusive scan of degrees
    int idx = lim + t;
    int v = (idx < N_NODES) ? deg[idx] : 0;
    s[t] = v;
    __syncthreads();
    #pragma unroll
    for (int off = 1; off < 256; off <<= 1) {
        int u = (t >= off) ? s[t - off] : 0;
        __syncthreads();
        s[t] += u;
        __syncthreads();
    }
    if (idx < N_NODES) rowptr[idx] = pb + s[t] - v;   // exclusive prefix
    if (idx == 0) rowptr[N_NODES] = N_EDGES;
}

// ---------------- gemm + distributed fill: every block does one 64-node tile, then ~384 edges ----------------
__global__ __launch_bounds__(256) void k_gemm_fill(const float* __restrict__ x,
                                                   const unsigned short* __restrict__ BhG,
                                                   unsigned short* __restrict__ zbuf,
                                                   unsigned short* __restrict__ y2buf,
                                                   const int* __restrict__ ei,
                                                   const float* __restrict__ ew,
                                                   const int* __restrict__ rowptr,
                                                   const int* __restrict__ rank,
                                                   uint2* __restrict__ eprs)
{
    __shared__ unsigned short Ah[64 * 128];   // 16 KB, [row][k] bf16, XOR-swizzled

    const int tid  = threadIdx.x;
    const int bm   = blockIdx.x * 64;
    const int wave = tid >> 6;
    const int lane = tid & 63;
    const int q    = lane >> 4;      // 0..3
    const int ln   = lane & 15;      // 0..15

    // ---- stage A: full 64x128 tile in ONE shot. thread (r, c) loads 32 floats. ----
    {
        const int r  = tid >> 2;         // 0..63
        const int c  = tid & 3;          // 0..3: float segment c*32 .. c*32+31
        const int gm = bm + r;
        const bool ok = gm < N_NODES;
        const float* px = &x[(size_t)gm * HID + c * 32];

        float4 v0 = make_float4(0.f,0.f,0.f,0.f), v1=v0, v2=v0, v3=v0, v4=v0, v5=v0, v6=v0, v7=v0;
        if (ok) {
            v0 = *(const float4*)(px + 0);  v1 = *(const float4*)(px + 4);
            v2 = *(const float4*)(px + 8);  v3 = *(const float4*)(px + 12);
            v4 = *(const float4*)(px + 16); v5 = *(const float4*)(px + 20);
            v6 = *(const float4*)(px + 24); v7 = *(const float4*)(px + 28);
        }
        uint4 ch0, ch1, ch2, ch3;        // 4 chunks of 16 B = 8 bf16 each
        ch0.x = pack2(v0.x, v0.y); ch0.y = pack2(v0.z, v0.w); ch0.z = pack2(v1.x, v1.y); ch0.w = pack2(v1.z, v1.w);
        ch1.x = pack2(v2.x, v2.y); ch1.y = pack2(v2.z, v2.w); ch1.z = pack2(v3.x, v3.y); ch1.w = pack2(v3.z, v3.w);
        ch2.x = pack2(v4.x, v4.y); ch2.y = pack2(v4.z, v4.w); ch2.z = pack2(v5.x, v5.y); ch2.w = pack2(v5.z, v5.w);
        ch3.x = pack2(v6.x, v6.y); ch3.y = pack2(v6.z, v6.w); ch3.z = pack2(v7.x, v7.y); ch3.w = pack2(v7.z, v7.w);

        // LDS write, swizzled: byte ^= ((row&7)<<4). row stride 256 B.
        char* rowp = (char*)Ah + r * 256;
        const int swz = (r & 7) << 4;
        *(uint4*)(rowp + ((c * 64 +  0) ^ swz)) = ch0;
        *(uint4*)(rowp + ((c * 64 + 16) ^ swz)) = ch1;
        *(uint4*)(rowp + ((c * 64 + 32) ^ swz)) = ch2;
        *(uint4*)(rowp + ((c * 64 + 48) ^ swz)) = ch3;

        // xbf half of zbuf (linear)
        if (ok) {
            unsigned short* zp = &zbuf[(size_t)gm * 256 + 128 + c * 32];
            *(uint4*)(zp + 0)  = ch0;
            *(uint4*)(zp + 8)  = ch1;
            *(uint4*)(zp + 16) = ch2;
            *(uint4*)(zp + 24) = ch3;
        }
    }
    lds_barrier();   // single barrier; zbuf stores stay in flight

    // ---- fragments: ah[mt][ks], swizzled read (row&7 == ln&7) ----
    bf16x8 ah[4][4];
    {
        const int swzr = (ln & 7) << 4;
        #pragma unroll
        for (int mt = 0; mt < 4; ++mt) {
            const char* rowp = (const char*)Ah + (mt * 16 + ln) * 256;
            #pragma unroll
            for (int ks = 0; ks < 4; ++ks) {
                ah[mt][ks] = *(const bf16x8*)(rowp + ((ks * 64 + q * 16) ^ swzr));
            }
        }
    }

    // ---- 64 MFMA, swapped operands: D = W^T . x^T -> row=hidden-out, col=node ----
    f32x4 acc[4][4] = {};            // [node-tile mt][out-tile nt]
    #pragma unroll
    for (int nt = 0; nt < 4; ++nt) {
        bf16x8 bh[4];
        #pragma unroll
        for (int ks = 0; ks < 4; ++ks) {
            bh[ks] = *(const bf16x8*)&BhG[ks * 8192 + (wave * 64 + nt * 16 + ln) * 32 + q * 8];
        }
        #pragma unroll
        for (int mt = 0; mt < 4; ++mt) {
            #pragma unroll
            for (int ks = 0; ks < 4; ++ks) {
                acc[mt][nt] = __builtin_amdgcn_mfma_f32_16x16x32_bf16(bh[ks], ah[mt][ks], acc[mt][nt], 0, 0, 0);
            }
        }
    }

    // ---- epilogue: D col=ln -> node, row=q*4+r -> hidden-out; one uint2 per (mt,nt) ----
    #pragma unroll
    for (int mt = 0; mt < 4; ++mt) {
        int node = bm + mt * 16 + ln;
        if (node < N_NODES) {
            #pragma unroll
            for (int nt = 0; nt < 4; ++nt) {
                int col0 = wave * 64 + nt * 16 + q * 4;
                unsigned int lo = pack2(acc[mt][nt][0], acc[mt][nt][1]);
                unsigned int hi = pack2(acc[mt][nt][2], acc[mt][nt][3]);
                if (col0 < 128) *(uint2*)&zbuf[(size_t)node * 256 + col0] = make_uint2(lo, hi);
                else            *(uint2*)&y2buf[(size_t)node * 128 + (col0 - 128)] = make_uint2(lo, hi);
            }
        }
    }

    // ---- distributed fill: this block's ~384-edge slice (no atomics: pos = rowptr[tgt] + rank[e]).
    // Overlaps other blocks' gemm phases; no low-occupancy tail.
    {
        int e0 = blockIdx.x * EDGES_PER_BLOCK;
        int e1 = e0 + EDGES_PER_BLOCK; if (e1 > N_EDGES) e1 = N_EDGES;
        for (int e = e0 + tid; e < e1; e += 256) {
            int tgt = ei[N_EDGES + e];
            int pos = rowptr[tgt] + rank[e];
            eprs[pos] = make_uint2((unsigned int)ei[e], __float_as_uint(ew[e]));
        }
    }
}

// ---------------- fused scores + softmax + aggregation: 8 edges / iteration ----------------
__global__ __launch_bounds__(256) void k_fused(const unsigned int* __restrict__ zu,
                                               const unsigned int* __restrict__ y2u,
                                               const int* __restrict__ rowptr,
                                               const uint2* __restrict__ eprs,
                                               const float* __restrict__ x,
                                               const float* __restrict__ W1,
                                               const float* __restrict__ b1,
                                               const float* __restrict__ W2,
                                               const float* __restrict__ b2,
                                               float* __restrict__ out)
{
    int n = (blockIdx.x * blockDim.x + threadIdx.x) >> 6;
    int lane = threadIdx.x & 63;
    if (n >= N_NODES) return;
    int ql = lane & 15;      // position within quarter: cols ql*8 .. ql*8+7
    int qi = lane >> 4;      // quarter index 0..3 (edge slot)
    int c0 = ql * 8;

    // per-lane constants for 8 cols
    uint4 uy2 = *(const uint4*)&y2u[(size_t)n * 64 + ql * 4];
    float2 y2a = bfpair(uy2.x), y2b = bfpair(uy2.y), y2c = bfpair(uy2.z), y2d = bfpair(uy2.w);
    float4 bv0 = *(const float4*)&b1[c0];
    float4 bv1 = *(const float4*)&b1[c0 + 4];
    float4 wr0 = *(const float4*)&W1[256 * HID + c0];
    float4 wr1 = *(const float4*)&W1[256 * HID + c0 + 4];
    float4 w20 = *(const float4*)&W2[c0];
    float4 w21 = *(const float4*)&W2[c0 + 4];
    float p0 = y2a.x + bv0.x, p1 = y2a.y + bv0.y, p2 = y2b.x + bv0.z, p3 = y2b.y + bv0.w;
    float p4 = y2c.x + bv1.x, p5 = y2c.y + bv1.y, p6 = y2d.x + bv1.z, p7 = y2d.y + bv1.w;
    float b2v = b2[0];

    int beg = rowptr[n], end = rowptr[n + 1];
    float a0 = 0.f, a1 = 0.f, a2 = 0.f, a3 = 0.f;
    float a4 = 0.f, a5 = 0.f, a6 = 0.f, a7 = 0.f;
    float denom = 0.f;

    for (int i = beg; i < end; i += 8) {
        // two edge slots per quarter: A = i+qi, B = i+4+qi. Issue ALL loads first.
        int idxA = i + qi;
        int idxB = i + 4 + qi;
        bool vA = idxA < end;
        bool vB = idxB < end;
        int ieA = vA ? idxA : (end - 1);
        int ieB = vB ? idxB : (end - 1);
        uint2 epA = eprs[ieA];
        uint2 epB = eprs[ieB];
        size_t baseA = (size_t)epA.x * 128;
        size_t baseB = (size_t)epB.x * 128;
        float wa = __uint_as_float(epA.y);
        float wb = __uint_as_float(epB.y);
        uint4 uyA = *(const uint4*)&zu[baseA + ql * 4];
        uint4 uxA = *(const uint4*)&zu[baseA + 64 + ql * 4];
        uint4 uyB = *(const uint4*)&zu[baseB + ql * 4];
        uint4 uxB = *(const uint4*)&zu[baseB + 64 + ql * 4];

        // ---- edge A score ----
        float2 ya = bfpair(uyA.x), yb = bfpair(uyA.y), yc = bfpair(uyA.z), yd = bfpair(uyA.w);
        float h0 = fmaxf(fmaf(wa, wr0.x, ya.x + p0), 0.f);
        float h1 = fmaxf(fmaf(wa, wr0.y, ya.y + p1), 0.f);
        float h2 = fmaxf(fmaf(wa, wr0.z, yb.x + p2), 0.f);
        float h3 = fmaxf(fmaf(wa, wr0.w, yb.y + p3), 0.f);
        float h4 = fmaxf(fmaf(wa, wr1.x, yc.x + p4), 0.f);
        float h5 = fmaxf(fmaf(wa, wr1.y, yc.y + p5), 0.f);
        float h6 = fmaxf(fmaf(wa, wr1.z, yd.x + p6), 0.f);
        float h7 = fmaxf(fmaf(wa, wr1.w, yd.y + p7), 0.f);
        float sA = ((h0 * w20.x + h1 * w20.y) + (h2 * w20.z + h3 * w20.w))
                 + ((h4 * w21.x + h5 * w21.y) + (h6 * w21.z + h7 * w21.w));

        // ---- edge B score (independent chain) ----
        float2 za = bfpair(uyB.x), zb = bfpair(uyB.y), zc = bfpair(uyB.z), zd = bfpair(uyB.w);
        float g0 = fmaxf(fmaf(wb, wr0.x, za.x + p0), 0.f);
        float g1 = fmaxf(fmaf(wb, wr0.y, za.y + p1), 0.f);
        float g2 = fmaxf(fmaf(wb, wr0.z, zb.x + p2), 0.f);
        float g3 = fmaxf(fmaf(wb, wr0.w, zb.y + p3), 0.f);
        float g4 = fmaxf(fmaf(wb, wr1.x, zc.x + p4), 0.f);
        float g5 = fmaxf(fmaf(wb, wr1.y, zc.y + p5), 0.f);
        float g6 = fmaxf(fmaf(wb, wr1.z, zd.x + p6), 0.f);
        float g7 = fmaxf(fmaf(wb, wr1.w, zd.y + p7), 0.f);
        float sB = ((g0 * w20.x + g1 * w20.y) + (g2 * w20.z + g3 * w20.w))
                 + ((g4 * w21.x + g5 * w21.y) + (g6 * w21.z + g7 * w21.w));

        // reduce within quarter — two independent chains
        #pragma unroll
        for (int m = 1; m <= 8; m <<= 1) {
            sA += __shfl_xor(sA, m, 64);
            sB += __shfl_xor(sB, m, 64);
        }
        float esA = vA ? __expf(sA + b2v) : 0.f;
        float esB = vB ? __expf(sB + b2v) : 0.f;

        float2 xa = bfpair(uxA.x), xb = bfpair(uxA.y), xc = bfpair(uxA.z), xd = bfpair(uxA.w);
        float2 ua = bfpair(uxB.x), ub = bfpair(uxB.y), uc = bfpair(uxB.z), ud = bfpair(uxB.w);
        a0 = fmaf(esA, xa.x, fmaf(esB, ua.x, a0));
        a1 = fmaf(esA, xa.y, fmaf(esB, ua.y, a1));
        a2 = fmaf(esA, xb.x, fmaf(esB, ub.x, a2));
        a3 = fmaf(esA, xb.y, fmaf(esB, ub.y, a3));
        a4 = fmaf(esA, xc.x, fmaf(esB, uc.x, a4));
        a5 = fmaf(esA, xc.y, fmaf(esB, uc.y, a5));
        a6 = fmaf(esA, xd.x, fmaf(esB, ud.x, a6));
        a7 = fmaf(esA, xd.y, fmaf(esB, ud.y, a7));
        denom += esA + esB;
    }

    // merge quarters (each quarter's lane ql covers the same 8 cols)
    #pragma unroll
    for (int m = 16; m <= 32; m <<= 1) {
        a0 += __shfl_xor(a0, m, 64); a1 += __shfl_xor(a1, m, 64);
        a2 += __shfl_xor(a2, m, 64); a3 += __shfl_xor(a3, m, 64);
        a4 += __shfl_xor(a4, m, 64); a5 += __shfl_xor(a5, m, 64);
        a6 += __shfl_xor(a6, m, 64); a7 += __shfl_xor(a7, m, 64);
        denom += __shfl_xor(denom, m, 64);
    }

    if (qi == 0) {
        float4 xt0 = *(const float4*)&x[(size_t)n * HID + c0];
        float4 xt1 = *(const float4*)&x[(size_t)n * HID + c0 + 4];
        float inv = 1.0f / fmaxf(denom, 1e-12f);
        float4 o0, o1;
        o0.x = xt0.x + a0 * inv; o0.y = xt0.y + a1 * inv;
        o0.z = xt0.z + a2 * inv; o0.w = xt0.w + a3 * inv;
        o1.x = xt1.x + a4 * inv; o1.y = xt1.y + a5 * inv;
        o1.z = xt1.z + a6 * inv; o1.w = xt1.w + a7 * inv;
        *(float4*)&out[(size_t)n * HID + c0]     = o0;
        *(float4*)&out[(size_t)n * HID + c0 + 4] = o1;
    }
}

// ---------------- launch ----------------
extern "C" void kernel_launch(void* const* d_in, const int* in_sizes, int n_in,
                              void* d_out, int out_size, void* d_ws, size_t ws_size,
                              hipStream_t stream) {
    const float* x  = (const float*)d_in[0];
    const int*   ei = (const int*)d_in[1];
    const float* ew = (const float*)d_in[2];
    const float* W1 = (const float*)d_in[3];
    const float* b1 = (const float*)d_in[4];
    const float* W2 = (const float*)d_in[5];
    const float* b2 = (const float*)d_in[6];
    float* out = (float*)d_out;
    char* ws = (char*)d_ws;

    const size_t deg_b    = 400000;
    const size_t rowptr_b = 400016;
    const size_t rank_b   = 2400000;     // N_EDGES * 4
    const size_t eprs_b   = 4800000;     // N_EDGES * 8
    const size_t Bh_b     = 65536;

    char* p = ws;
    int* deg      = (int*)p;             p += deg_b;
    int* rowptr   = (int*)p;             p += rowptr_b;
    int* rank     = (int*)p;             p += rank_b;
    uint2* eprs   = (uint2*)p;           p += eprs_b;
    unsigned short* BhG = (unsigned short*)p;  p += Bh_b;
    unsigned short* zbuf  = (unsigned short*)p;  p += (size_t)N_NODES * 256 * 2;  // 51.2 MB
    unsigned short* y2buf = (unsigned short*)p;                                   // 25.6 MB

    const int edge_blocks = (N_EDGES + 255) / 256;
    const int node_wave_blocks = (N_NODES * 64 + 255) / 256;

    hipLaunchKernelGGL(k_prep,   dim3(SCAN_NB), dim3(256), 0, stream, W1, BhG, deg);
    hipLaunchKernelGGL(k_count,  dim3(edge_blocks), dim3(256), 0, stream, ei, deg, rank);
    hipLaunchKernelGGL(k_rowptr, dim3(SCAN_NB), dim3(256), 0, stream, deg, rowptr);
    hipLaunchKernelGGL(k_gemm_fill, dim3(GEMM_BLOCKS), dim3(256), 0, stream,
                       x, BhG, zbuf, y2buf, ei, ew, rowptr, rank, eprs);
    hipLaunchKernelGGL(k_fused,  dim3(node_wave_blocks), dim3(256), 0, stream,
                       (const unsigned int*)zbuf, (const unsigned int*)y2buf,
                       rowptr, eprs, x, W1, b1, W2, b2, out);
}

// Round 9
// 301.173 us; speedup vs baseline: 1.0864x; 1.0556x over previous
//
#include <hip/hip_runtime.h>
#include <hip/hip_bf16.h>

#define N_NODES 100000
#define N_EDGES 600000
#define HID 128
#define SCAN_NB 391          // ceil(N_NODES/256)
#define GEMM_BLOCKS 1563     // ceil(N_NODES/64)
#define COUNT_BLOCKS 586

// zbuf[n] = 256 bf16: [0:128) y1 = x@W1[0:128] (gathered, src role), [128:256) xbf = bf16(x[n])
// y2buf[n] = 128 bf16: x@W1[128:256] (sequential, tgt role)
// eprs[pos] = (uint src, float-bits w) in CSR-by-target order (within-node order = count order)

typedef short bf16x8 __attribute__((ext_vector_type(8)));
typedef float f32x4  __attribute__((ext_vector_type(4)));

// ---------------- helpers ----------------
__device__ inline unsigned short f2bf(float v) {
    __hip_bfloat16 h = __float2bfloat16(v);
    return *(unsigned short*)&h;
}
__device__ inline unsigned int pack2(float a, float b) {
    return (unsigned int)f2bf(a) | ((unsigned int)f2bf(b) << 16);
}
__device__ inline float2 bfpair(unsigned int u) {
    float lo = __uint_as_float(u << 16);
    float hi = __uint_as_float(u & 0xffff0000u);
    return make_float2(lo, hi);
}
// LDS-only barrier: orders ds ops; in-flight global stores may stay in flight.
__device__ inline void lds_barrier() {
    asm volatile("s_waitcnt lgkmcnt(0)" ::: "memory");
    __builtin_amdgcn_s_barrier();
}

// ---------------- W1 -> blocked bf16 [ks][n][kl]  (128 blocks, ~2 us) ----------------
__global__ __launch_bounds__(256) void k_prepW1(const float* __restrict__ W1,
                                                unsigned short* __restrict__ Bh)
{
    int idx = blockIdx.x * 256 + threadIdx.x;     // 0 .. 32767
    int n = idx & 255;
    int k = idx >> 8;                             // 0 .. 127
    float v = (n < HID) ? W1[k * HID + n] : W1[(HID + k) * HID + (n - HID)];
    Bh[(k >> 5) * 8192 + n * 32 + (k & 31)] = f2bf(v);
}

// ---------------- hybrid: gemm (blocks 0..1562) + degree-count tail (L2-benign) ----------------
__global__ __launch_bounds__(256) void k_gemm_count(const float* __restrict__ x,
                                                    const unsigned short* __restrict__ BhG,
                                                    unsigned short* __restrict__ zbuf,
                                                    unsigned short* __restrict__ y2buf,
                                                    const int* __restrict__ ei,
                                                    int* __restrict__ deg,
                                                    int* __restrict__ rank)
{
    __shared__ unsigned short Ah[64 * 128];   // 16 KB, [row][k] bf16, XOR-swizzled

    if (blockIdx.x >= GEMM_BLOCKS) {
        // ---- count role: 400 KB atomic footprint, coalesced ei reads — hides under gemm ----
        int cb = blockIdx.x - GEMM_BLOCKS;
        for (int e = cb * 256 + threadIdx.x; e < N_EDGES; e += COUNT_BLOCKS * 256) {
            rank[e] = atomicAdd(&deg[ei[N_EDGES + e]], 1);
        }
        return;
    }

    const int tid  = threadIdx.x;
    const int bm   = blockIdx.x * 64;
    const int wave = tid >> 6;
    const int lane = tid & 63;
    const int q    = lane >> 4;      // 0..3
    const int ln   = lane & 15;      // 0..15

    // ---- stage A: full 64x128 tile in ONE shot. thread (r, c) loads 32 floats. ----
    {
        const int r  = tid >> 2;         // 0..63
        const int c  = tid & 3;          // 0..3: float segment c*32 .. c*32+31
        const int gm = bm + r;
        const bool ok = gm < N_NODES;
        const float* px = &x[(size_t)gm * HID + c * 32];

        float4 v0 = make_float4(0.f,0.f,0.f,0.f), v1=v0, v2=v0, v3=v0, v4=v0, v5=v0, v6=v0, v7=v0;
        if (ok) {
            v0 = *(const float4*)(px + 0);  v1 = *(const float4*)(px + 4);
            v2 = *(const float4*)(px + 8);  v3 = *(const float4*)(px + 12);
            v4 = *(const float4*)(px + 16); v5 = *(const float4*)(px + 20);
            v6 = *(const float4*)(px + 24); v7 = *(const float4*)(px + 28);
        }
        uint4 ch0, ch1, ch2, ch3;        // 4 chunks of 16 B = 8 bf16 each
        ch0.x = pack2(v0.x, v0.y); ch0.y = pack2(v0.z, v0.w); ch0.z = pack2(v1.x, v1.y); ch0.w = pack2(v1.z, v1.w);
        ch1.x = pack2(v2.x, v2.y); ch1.y = pack2(v2.z, v2.w); ch1.z = pack2(v3.x, v3.y); ch1.w = pack2(v3.z, v3.w);
        ch2.x = pack2(v4.x, v4.y); ch2.y = pack2(v4.z, v4.w); ch2.z = pack2(v5.x, v5.y); ch2.w = pack2(v5.z, v5.w);
        ch3.x = pack2(v6.x, v6.y); ch3.y = pack2(v6.z, v6.w); ch3.z = pack2(v7.x, v7.y); ch3.w = pack2(v7.z, v7.w);

        // LDS write, swizzled: byte ^= ((row&7)<<4). row stride 256 B.
        char* rowp = (char*)Ah + r * 256;
        const int swz = (r & 7) << 4;
        *(uint4*)(rowp + ((c * 64 +  0) ^ swz)) = ch0;
        *(uint4*)(rowp + ((c * 64 + 16) ^ swz)) = ch1;
        *(uint4*)(rowp + ((c * 64 + 32) ^ swz)) = ch2;
        *(uint4*)(rowp + ((c * 64 + 48) ^ swz)) = ch3;

        // xbf half of zbuf (linear)
        if (ok) {
            unsigned short* zp = &zbuf[(size_t)gm * 256 + 128 + c * 32];
            *(uint4*)(zp + 0)  = ch0;
            *(uint4*)(zp + 8)  = ch1;
            *(uint4*)(zp + 16) = ch2;
            *(uint4*)(zp + 24) = ch3;
        }
    }
    lds_barrier();   // single barrier; zbuf stores stay in flight

    // ---- fragments: ah[mt][ks], swizzled read (row&7 == ln&7) ----
    bf16x8 ah[4][4];
    {
        const int swzr = (ln & 7) << 4;
        #pragma unroll
        for (int mt = 0; mt < 4; ++mt) {
            const char* rowp = (const char*)Ah + (mt * 16 + ln) * 256;
            #pragma unroll
            for (int ks = 0; ks < 4; ++ks) {
                ah[mt][ks] = *(const bf16x8*)(rowp + ((ks * 64 + q * 16) ^ swzr));
            }
        }
    }

    // ---- 64 MFMA, swapped operands: D = W^T . x^T -> row=hidden-out, col=node ----
    f32x4 acc[4][4] = {};            // [node-tile mt][out-tile nt]
    #pragma unroll
    for (int nt = 0; nt < 4; ++nt) {
        bf16x8 bh[4];
        #pragma unroll
        for (int ks = 0; ks < 4; ++ks) {
            bh[ks] = *(const bf16x8*)&BhG[ks * 8192 + (wave * 64 + nt * 16 + ln) * 32 + q * 8];
        }
        #pragma unroll
        for (int mt = 0; mt < 4; ++mt) {
            #pragma unroll
            for (int ks = 0; ks < 4; ++ks) {
                acc[mt][nt] = __builtin_amdgcn_mfma_f32_16x16x32_bf16(bh[ks], ah[mt][ks], acc[mt][nt], 0, 0, 0);
            }
        }
    }

    // ---- epilogue: D col=ln -> node, row=q*4+r -> hidden-out; one uint2 per (mt,nt) ----
    #pragma unroll
    for (int mt = 0; mt < 4; ++mt) {
        int node = bm + mt * 16 + ln;
        if (node < N_NODES) {
            #pragma unroll
            for (int nt = 0; nt < 4; ++nt) {
                int col0 = wave * 64 + nt * 16 + q * 4;
                unsigned int lo = pack2(acc[mt][nt][0], acc[mt][nt][1]);
                unsigned int hi = pack2(acc[mt][nt][2], acc[mt][nt][3]);
                if (col0 < 128) *(uint2*)&zbuf[(size_t)node * 256 + col0] = make_uint2(lo, hi);
                else            *(uint2*)&y2buf[(size_t)node * 128 + (col0 - 128)] = make_uint2(lo, hi);
            }
        }
    }
}

// ---------------- CSR: rowptr (global prefix computed per-block from L2-hot deg) ----------------
__global__ __launch_bounds__(256) void k_rowptr(const int* __restrict__ deg,
                                                int* __restrict__ rowptr)
{
    __shared__ int s[256];
    int t = threadIdx.x;
    int b = blockIdx.x;
    int lim = b * 256;

    // base = sum of deg[0..lim) — 400 KB array is L2-resident
    int acc = 0;
    for (int i = t; i < lim; i += 256) acc += deg[i];
    s[t] = acc;
    __syncthreads();
    #pragma unroll
    for (int off = 128; off > 0; off >>= 1) {
        if (t < off) s[t] += s[t + off];
        __syncthreads();
    }
    int pb = s[0];
    __syncthreads();

    // block-local inclusive scan of degrees
    int idx = lim + t;
    int v = (idx < N_NODES) ? deg[idx] : 0;
    s[t] = v;
    __syncthreads();
    #pragma unroll
    for (int off = 1; off < 256; off <<= 1) {
        int u = (t >= off) ? s[t - off] : 0;
        __syncthreads();
        s[t] += u;
        __syncthreads();
    }
    if (idx < N_NODES) rowptr[idx] = pb + s[t] - v;   // exclusive prefix
    if (idx == 0) rowptr[N_NODES] = N_EDGES;
}

// ---------------- CSR fill: rank-based, NO atomics; own dispatch (time-separated from gemm) ----------------
__global__ __launch_bounds__(256) void k_fill(const int* __restrict__ ei,
                                              const float* __restrict__ ew,
                                              const int* __restrict__ rowptr,
                                              const int* __restrict__ rank,
                                              uint2* __restrict__ eprs)
{
    for (int e = blockIdx.x * 256 + threadIdx.x; e < N_EDGES; e += COUNT_BLOCKS * 256) {
        int tgt = ei[N_EDGES + e];
        int pos = rowptr[tgt] + rank[e];
        eprs[pos] = make_uint2((unsigned int)ei[e], __float_as_uint(ew[e]));
    }
}

// ---------------- fused scores + softmax + aggregation: 4 edges / iteration (proven 78 us body) ----------------
__global__ __launch_bounds__(256) void k_fused(const unsigned int* __restrict__ zu,
                                               const unsigned int* __restrict__ y2u,
                                               const int* __restrict__ rowptr,
                                               const uint2* __restrict__ eprs,
                                               const float* __restrict__ x,
                                               const float* __restrict__ W1,
                                               const float* __restrict__ b1,
                                               const float* __restrict__ W2,
                                               const float* __restrict__ b2,
                                               float* __restrict__ out)
{
    int n = (blockIdx.x * blockDim.x + threadIdx.x) >> 6;
    int lane = threadIdx.x & 63;
    if (n >= N_NODES) return;
    int ql = lane & 15;      // position within quarter: cols ql*8 .. ql*8+7
    int qi = lane >> 4;      // quarter index 0..3 (edge slot)
    int c0 = ql * 8;

    // per-lane constants for 8 cols
    uint4 uy2 = *(const uint4*)&y2u[(size_t)n * 64 + ql * 4];
    float2 y2a = bfpair(uy2.x), y2b = bfpair(uy2.y), y2c = bfpair(uy2.z), y2d = bfpair(uy2.w);
    float4 bv0 = *(const float4*)&b1[c0];
    float4 bv1 = *(const float4*)&b1[c0 + 4];
    float4 wr0 = *(const float4*)&W1[256 * HID + c0];
    float4 wr1 = *(const float4*)&W1[256 * HID + c0 + 4];
    float4 w20 = *(const float4*)&W2[c0];
    float4 w21 = *(const float4*)&W2[c0 + 4];
    float p0 = y2a.x + bv0.x, p1 = y2a.y + bv0.y, p2 = y2b.x + bv0.z, p3 = y2b.y + bv0.w;
    float p4 = y2c.x + bv1.x, p5 = y2c.y + bv1.y, p6 = y2d.x + bv1.z, p7 = y2d.y + bv1.w;
    float b2v = b2[0];

    int beg = rowptr[n], end = rowptr[n + 1];
    float a0 = 0.f, a1 = 0.f, a2 = 0.f, a3 = 0.f;
    float a4 = 0.f, a5 = 0.f, a6 = 0.f, a7 = 0.f;
    float denom = 0.f;

    for (int i = beg; i < end; i += 4) {
        int idx = i + qi;
        bool valid = idx < end;
        int ie = valid ? idx : (end - 1);
        uint2 ep = eprs[ie];
        size_t base = (size_t)ep.x * 128;
        float w = __uint_as_float(ep.y);
        uint4 uy = *(const uint4*)&zu[base + ql * 4];
        uint4 ux = *(const uint4*)&zu[base + 64 + ql * 4];

        float2 ya = bfpair(uy.x), yb = bfpair(uy.y), yc = bfpair(uy.z), yd = bfpair(uy.w);
        float h0 = fmaxf(fmaf(w, wr0.x, ya.x + p0), 0.f);
        float h1 = fmaxf(fmaf(w, wr0.y, ya.y + p1), 0.f);
        float h2 = fmaxf(fmaf(w, wr0.z, yb.x + p2), 0.f);
        float h3 = fmaxf(fmaf(w, wr0.w, yb.y + p3), 0.f);
        float h4 = fmaxf(fmaf(w, wr1.x, yc.x + p4), 0.f);
        float h5 = fmaxf(fmaf(w, wr1.y, yc.y + p5), 0.f);
        float h6 = fmaxf(fmaf(w, wr1.z, yd.x + p6), 0.f);
        float h7 = fmaxf(fmaf(w, wr1.w, yd.y + p7), 0.f);
        float s = ((h0 * w20.x + h1 * w20.y) + (h2 * w20.z + h3 * w20.w))
                + ((h4 * w21.x + h5 * w21.y) + (h6 * w21.z + h7 * w21.w));
        // reduce within quarter (xor masks 1,2,4,8 stay in the 16-lane group)
        #pragma unroll
        for (int m = 1; m <= 8; m <<= 1) s += __shfl_xor(s, m, 64);
        float es = valid ? __expf(s + b2v) : 0.f;

        float2 xa = bfpair(ux.x), xb = bfpair(ux.y), xc = bfpair(ux.z), xd = bfpair(ux.w);
        a0 = fmaf(es, xa.x, a0); a1 = fmaf(es, xa.y, a1);
        a2 = fmaf(es, xb.x, a2); a3 = fmaf(es, xb.y, a3);
        a4 = fmaf(es, xc.x, a4); a5 = fmaf(es, xc.y, a5);
        a6 = fmaf(es, xd.x, a6); a7 = fmaf(es, xd.y, a7);
        denom += es;
    }

    // merge quarters (each quarter's lane ql covers the same 8 cols)
    #pragma unroll
    for (int m = 16; m <= 32; m <<= 1) {
        a0 += __shfl_xor(a0, m, 64); a1 += __shfl_xor(a1, m, 64);
        a2 += __shfl_xor(a2, m, 64); a3 += __shfl_xor(a3, m, 64);
        a4 += __shfl_xor(a4, m, 64); a5 += __shfl_xor(a5, m, 64);
        a6 += __shfl_xor(a6, m, 64); a7 += __shfl_xor(a7, m, 64);
        denom += __shfl_xor(denom, m, 64);
    }

    if (qi == 0) {
        float4 xt0 = *(const float4*)&x[(size_t)n * HID + c0];
        float4 xt1 = *(const float4*)&x[(size_t)n * HID + c0 + 4];
        float inv = 1.0f / fmaxf(denom, 1e-12f);
        float4 o0, o1;
        o0.x = xt0.x + a0 * inv; o0.y = xt0.y + a1 * inv;
        o0.z = xt0.z + a2 * inv; o0.w = xt0.w + a3 * inv;
        o1.x = xt1.x + a4 * inv; o1.y = xt1.y + a5 * inv;
        o1.z = xt1.z + a6 * inv; o1.w = xt1.w + a7 * inv;
        *(float4*)&out[(size_t)n * HID + c0]     = o0;
        *(float4*)&out[(size_t)n * HID + c0 + 4] = o1;
    }
}

// ---------------- launch ----------------
extern "C" void kernel_launch(void* const* d_in, const int* in_sizes, int n_in,
                              void* d_out, int out_size, void* d_ws, size_t ws_size,
                              hipStream_t stream) {
    const float* x  = (const float*)d_in[0];
    const int*   ei = (const int*)d_in[1];
    const float* ew = (const float*)d_in[2];
    const float* W1 = (const float*)d_in[3];
    const float* b1 = (const float*)d_in[4];
    const float* W2 = (const float*)d_in[5];
    const float* b2 = (const float*)d_in[6];
    float* out = (float*)d_out;
    char* ws = (char*)d_ws;

    const size_t deg_b    = 400000;
    const size_t rowptr_b = 400016;
    const size_t rank_b   = 2400000;     // N_EDGES * 4
    const size_t eprs_b   = 4800000;     // N_EDGES * 8
    const size_t Bh_b     = 65536;

    char* p = ws;
    int* deg      = (int*)p;             p += deg_b;
    int* rowptr   = (int*)p;             p += rowptr_b;
    int* rank     = (int*)p;             p += rank_b;
    uint2* eprs   = (uint2*)p;           p += eprs_b;
    unsigned short* BhG = (unsigned short*)p;  p += Bh_b;
    unsigned short* zbuf  = (unsigned short*)p;  p += (size_t)N_NODES * 256 * 2;  // 51.2 MB
    unsigned short* y2buf = (unsigned short*)p;                                   // 25.6 MB

    const int node_wave_blocks = (N_NODES * 64 + 255) / 256;

    hipMemsetAsync(deg, 0, 400000, stream);
    hipLaunchKernelGGL(k_prepW1, dim3(128), dim3(256), 0, stream, W1, BhG);
    hipLaunchKernelGGL(k_gemm_count, dim3(GEMM_BLOCKS + COUNT_BLOCKS), dim3(256), 0, stream,
                       x, BhG, zbuf, y2buf, ei, deg, rank);
    hipLaunchKernelGGL(k_rowptr, dim3(SCAN_NB), dim3(256), 0, stream, deg, rowptr);
    hipLaunchKernelGGL(k_fill,   dim3(COUNT_BLOCKS), dim3(256), 0, stream, ei, ew, rowptr, rank, eprs);
    hipLaunchKernelGGL(k_fused,  dim3(node_wave_blocks), dim3(256), 0, stream,
                       (const unsigned int*)zbuf, (const unsigned int*)y2buf,
                       rowptr, eprs, x, W1, b1, W2, b2, out);
}